// Round 8
// baseline (185.490 us; speedup 1.0000x reference)
//
#include <hip/hip_runtime.h>
#include <cstdint>

typedef __attribute__((ext_vector_type(8))) short short8;      // 8 bf16 = 4 VGPRs
typedef __attribute__((ext_vector_type(4))) float floatx4;     // 16x16 MFMA C/D frag
typedef __attribute__((ext_vector_type(16))) float floatx16;   // 32x32 MFMA C/D frag
typedef __attribute__((ext_vector_type(8))) _Float16 half8;    // 32x32x16 f16 A/B frag

#define DEV __device__ __forceinline__

constexpr int NB = 2, Lseq = 2048, NH = 16, HD = 64, EMB = 1024;
// fold softmax scale (1/sqrt(1024)) and log2(e) into Wq so flash uses exp2
constexpr float QSCALE = 0.03125f * 1.4426950408889634f;

// pack two f32 -> two bf16 in one dword (round-half-up via bias, then v_perm)
DEV uint32_t pack2(float lo, float hi) {
  uint32_t a = __builtin_bit_cast(uint32_t, lo) + 0x8000u;
  uint32_t b = __builtin_bit_cast(uint32_t, hi) + 0x8000u;
  return __builtin_amdgcn_perm(b, a, 0x07060302);
}

DEV uint32_t packh2(float lo, float hi) {  // two f32 -> packed f16 dword
  return __builtin_bit_cast(uint32_t, __builtin_amdgcn_cvt_pkrtz(lo, hi));
}

DEV void gl_lds16(const void* g, void* l) {  // async global->LDS, 16B/lane
  __builtin_amdgcn_global_load_lds((const __attribute__((address_space(1))) void*)g,
                                   (__attribute__((address_space(3))) void*)l, 16, 0, 0);
}

// half-wave exchange: after call, x = [x_lo, y_lo], y = [x_hi, y_hi] (lane blocks of 32)
DEV void pl32(uint32_t& x, uint32_t& y) {
  typedef __attribute__((ext_vector_type(2))) unsigned int uint2v;
  uint2v r = __builtin_amdgcn_permlane32_swap(x, y, false, false);
  x = r[0];
  y = r[1];
}

// load 8 consecutive f32, scale, convert to a bf16 MFMA frag chunk
DEV short8 ld8bf(const float* p, float sc) {
  float4 u = *(const float4*)p;
  float4 v = *(const float4*)(p + 4);
  union { short8 s; uint32_t d[4]; } r;
  r.d[0] = pack2(u.x * sc, u.y * sc);
  r.d[1] = pack2(u.z * sc, u.w * sc);
  r.d[2] = pack2(v.x * sc, v.y * sc);
  r.d[3] = pack2(v.z * sc, v.w * sc);
  return r.s;
}

// ---------------- prep: Q/K/V projections (MFMA, LDS-free) + Wout cvt ----------------
// (R5 version — the coalesced-store rewrite (R7) measured no gain; reverted.)
__global__ __launch_bounds__(256) void prep_kernel(
    const float* __restrict__ values, const float* __restrict__ keysrc,
    const float* __restrict__ query, const float* __restrict__ Wv,
    const float* __restrict__ Wk, const float* __restrict__ Wq,
    const float* __restrict__ Wout,
    uint16_t* __restrict__ qp, uint16_t* __restrict__ kp,
    uint16_t* __restrict__ vp, uint16_t* __restrict__ wbf) {
  const int t = threadIdx.x, w = t >> 6, lane = t & 63;
  const int quad = lane >> 4, l16 = lane & 15;
  const int wid = blockIdx.x * 4 + w;
  const int mat = wid >> 10, sub = wid & 1023;

  if (mat == 3) {  // Wout f32 -> bf16
#pragma unroll
    for (int i = 0; i < 4; ++i) {
      int idx = sub * 256 + i * 64 + lane;
      float4 v = ((const float4*)Wout)[idx];
      uint2 p;
      p.x = pack2(v.x, v.y);
      p.y = pack2(v.z, v.w);
      ((uint2*)wbf)[idx] = p;
    }
    return;
  }

  floatx4 c[4][4];
#pragma unroll
  for (int i = 0; i < 4; ++i)
#pragma unroll
    for (int j = 0; j < 4; ++j) c[i][j] = floatx4{0.f, 0.f, 0.f, 0.f};

  if (mat < 2) {
    const float* src = mat ? keysrc : query;
    const float* W   = mat ? Wk : Wq;
    const float asc  = mat ? 1.f : QSCALE;
    uint16_t* dst    = mat ? kp : qp;
    const int R0 = sub * 64;
    short8 a[4][2], b[4][2];
#pragma unroll
    for (int dc = 0; dc < 2; ++dc) {
#pragma unroll
      for (int f = 0; f < 4; ++f) {
        a[f][dc] = ld8bf(W + (size_t)(f * 16 + l16) * 64 + dc * 32 + quad * 8, asc);
        b[f][dc] = ld8bf(src + (size_t)(R0 + f * 16 + l16) * 64 + dc * 32 + quad * 8, 1.f);
      }
    }
#pragma unroll
    for (int dc = 0; dc < 2; ++dc)
#pragma unroll
      for (int mf = 0; mf < 4; ++mf)
#pragma unroll
        for (int nf = 0; nf < 4; ++nf)
          c[mf][nf] = __builtin_amdgcn_mfma_f32_16x16x32_bf16(a[mf][dc], b[nf][dc], c[mf][nf], 0, 0, 0);
#pragma unroll
    for (int nf = 0; nf < 4; ++nf) {
      int r = R0 + nf * 16 + l16;
      int h = r & 15, l = (r >> 4) & 2047, n = r >> 15;
      uint16_t* drow = dst + ((size_t)(n * 16 + h) * 2048 + l) * 64;
#pragma unroll
      for (int mf = 0; mf < 4; ++mf) {
        uint2 pk;
        pk.x = pack2(c[mf][nf][0], c[mf][nf][1]);
        pk.y = pack2(c[mf][nf][2], c[mf][nf][3]);
        *(uint2*)(drow + mf * 16 + quad * 4) = pk;
      }
    }
  } else {
    const int nh = sub >> 5, L0 = (sub & 31) * 64;
    const int n = nh >> 4, h = nh & 15;
    short8 a[4][2], b[4][2];
#pragma unroll
    for (int dc = 0; dc < 2; ++dc) {
#pragma unroll
      for (int f = 0; f < 4; ++f) {
        a[f][dc] = ld8bf(values + (size_t)(n * 2048 + L0 + f * 16 + l16) * 1024 + h * 64 + dc * 32 + quad * 8, 1.f);
        b[f][dc] = ld8bf(Wv + (size_t)(f * 16 + l16) * 64 + dc * 32 + quad * 8, 1.f);
      }
    }
#pragma unroll
    for (int dc = 0; dc < 2; ++dc)
#pragma unroll
      for (int mf = 0; mf < 4; ++mf)
#pragma unroll
        for (int nf = 0; nf < 4; ++nf)
          c[mf][nf] = __builtin_amdgcn_mfma_f32_16x16x32_bf16(a[mf][dc], b[nf][dc], c[mf][nf], 0, 0, 0);
#pragma unroll
    for (int nf = 0; nf < 4; ++nf) {
      int d = nf * 16 + l16;
      uint16_t* drow = vp + ((size_t)nh * 64 + d) * 2048 + L0;
#pragma unroll
      for (int mf = 0; mf < 4; ++mf) {
        uint2 pk;
        pk.x = packh2(c[mf][nf][0], c[mf][nf][1]);
        pk.y = packh2(c[mf][nf][2], c[mf][nf][3]);
        *(uint2*)(drow + mf * 16 + quad * 4) = pk;
      }
    }
  }
}

// ---------------- Flash attention: 32x32 MFMA + kh-split = 16 waves/CU ---------------
// R6's 32x32 math (160 MFMA-cyc per 32q*64key vs 240 at 16x16; 16 conflict-free b128
// LDS reads, R6 measured 0 conflicts) at R0's occupancy (kh=2 split -> 4096 waves =
// 16/CU, 4 blocks/CU, 2-buf + __syncthreads). Epilogue dumps UNNORMALIZED O^T in f16
// pairs + per-q l (f32); out_gemm fuses the kh-combine into its X staging.
__global__ __launch_bounds__(256, 4) void flash_kernel(const uint16_t* __restrict__ qp,
                                                       const uint16_t* __restrict__ kp,
                                                       const uint16_t* __restrict__ vp,
                                                       uint32_t* __restrict__ opart,
                                                       float* __restrict__ psum) {
  constexpr int kbn = 16;
  __shared__ uint16_t Kt[2][64 * 64];    // swizzled [key][d] bf16
  __shared__ uint16_t Vt[2][64 * 64];    // swizzled [d][key] f16
  const int t = threadIdx.x;
  const int w = t >> 6, lane = t & 63, hi = lane >> 5, l32 = lane & 31;
  const int nh = blockIdx.x, qt = blockIdx.y, kh = blockIdx.z;
  const int q0w = qt * 128 + w * 32;     // 32 q-rows per wave
  const uint16_t* Qb = qp + (size_t)nh * Lseq * HD;
  const uint16_t* Kb = kp + (size_t)nh * Lseq * HD + (size_t)kh * 1024 * 64;
  const uint16_t* Vb = vp + (size_t)nh * HD * Lseq;
  const int vcol0 = kh * 1024;
  const int srow = lane >> 3, sc8 = (lane & 7) ^ (lane >> 3);  // staging swizzle base

  // Q B-frags (32x32x16: lane holds B[k=hi*8+i][col=l32], k = d within dc-slice)
  short8 bq[4];
#pragma unroll
  for (int dc = 0; dc < 4; ++dc)
    bq[dc] = *(const short8*)(Qb + (size_t)(q0w + l32) * 64 + dc * 16 + hi * 8);

  floatx16 o[2], lfr;   // O^T frags (dt=0,1) + ones-MFMA l accumulator
#pragma unroll
  for (int r = 0; r < 16; ++r) { o[0][r] = 0.f; o[1][r] = 0.f; lfr[r] = 0.f; }
  const _Float16 one = (_Float16)1.0f;
  const half8 vones = {one, one, one, one, one, one, one, one};

  auto stage = [&](int tile, int buf) {  // 4 DMA instrs/wave (8 groups over 4 waves)
#pragma unroll
    for (int i = 0; i < 2; ++i) {
      int r0 = w * 16 + i * 8;
      int sc = sc8 ^ ((w * 2 + i) & 3);  // (row>>3)&3 for rows r0..r0+7
      gl_lds16(Kb + (size_t)tile * 4096 + (r0 + srow) * 64 + sc * 8, &Kt[buf][r0 * 64]);
      gl_lds16(Vb + (size_t)(r0 + srow) * Lseq + vcol0 + tile * 64 + sc * 8, &Vt[buf][r0 * 64]);
    }
  };

  stage(0, 0);

  for (int kb = 0; kb < kbn; ++kb) {
    __syncthreads();
    const int cur = kb & 1;
    if (kb + 1 < kbn) stage(kb + 1, cur ^ 1);

#pragma unroll
    for (int kt = 0; kt < 2; ++kt) {
      // S^T(32keys x 32q) = K_tile · Q^T, K=16 per step over d=64
      floatx16 s;
#pragma unroll
      for (int r = 0; r < 16; ++r) s[r] = 0.f;
      const int krow = kt * 32 + l32;
      const int ksw = (krow & 7) ^ ((krow >> 3) & 3);
#pragma unroll
      for (int dc = 0; dc < 4; ++dc) {
        short8 ak = *(const short8*)(&Kt[cur][krow * 64 + (((dc << 1) | hi) ^ ksw) * 8]);
        s = __builtin_amdgcn_mfma_f32_32x32x16_bf16(ak, bq[dc], s, 0, 0, 0);
      }
      // p = exp2(s); repack to two 16-key B-frags via cvt_pkrtz + permlane32_swap.
      uint32_t a0 = packh2(__builtin_amdgcn_exp2f(s[0]), __builtin_amdgcn_exp2f(s[1]));
      uint32_t a1 = packh2(__builtin_amdgcn_exp2f(s[2]), __builtin_amdgcn_exp2f(s[3]));
      uint32_t b0 = packh2(__builtin_amdgcn_exp2f(s[4]), __builtin_amdgcn_exp2f(s[5]));
      uint32_t b1 = packh2(__builtin_amdgcn_exp2f(s[6]), __builtin_amdgcn_exp2f(s[7]));
      uint32_t c0 = packh2(__builtin_amdgcn_exp2f(s[8]), __builtin_amdgcn_exp2f(s[9]));
      uint32_t c1 = packh2(__builtin_amdgcn_exp2f(s[10]), __builtin_amdgcn_exp2f(s[11]));
      uint32_t d0 = packh2(__builtin_amdgcn_exp2f(s[12]), __builtin_amdgcn_exp2f(s[13]));
      uint32_t d1 = packh2(__builtin_amdgcn_exp2f(s[14]), __builtin_amdgcn_exp2f(s[15]));
      pl32(a0, b0); pl32(a1, b1); pl32(c0, d0); pl32(c1, d1);
      union { half8 h; uint32_t u[4]; } f0, f1;
      f0.u[0] = a0; f0.u[1] = a1; f0.u[2] = b0; f0.u[3] = b1;  // keys kt*32 + 0..15
      f1.u[0] = c0; f1.u[1] = c1; f1.u[2] = d0; f1.u[3] = d1;  // keys kt*32 + 16..31

      lfr = __builtin_amdgcn_mfma_f32_32x32x16_f16(vones, f0.h, lfr, 0, 0, 0);
      lfr = __builtin_amdgcn_mfma_f32_32x32x16_f16(vones, f1.h, lfr, 0, 0, 0);

      // O^T += V^T · P
#pragma unroll
      for (int dt = 0; dt < 2; ++dt) {
        const int vrow = dt * 32 + l32;
        const int vsw = (vrow & 7) ^ ((vrow >> 3) & 3);
        half8 av0 = *(const half8*)(&Vt[cur][vrow * 64 + ((kt * 4 + hi) ^ vsw) * 8]);
        o[dt] = __builtin_amdgcn_mfma_f32_32x32x16_f16(av0, f0.h, o[dt], 0, 0, 0);
        half8 av1 = *(const half8*)(&Vt[cur][vrow * 64 + ((kt * 4 + 2 + hi) ^ vsw) * 8]);
        o[dt] = __builtin_amdgcn_mfma_f32_32x32x16_f16(av1, f1.h, o[dt], 0, 0, 0);
      }
    }
  }

  // epilogue: dump raw O^T partial (f16 pairs, lane order) + l partial.
  // dword (dt*8+j) of lane = regs (2j,2j+1) = d-pair at d = dt*32 + d0(j) + 4*hi,
  // q = q0w + l32. out_gemm reconstructs with the same formula.
  uint32_t* ob = opart + ((size_t)(((nh * 16 + qt) * 2 + kh) * 4 + w)) * 1024 + lane;
#pragma unroll
  for (int dt = 0; dt < 2; ++dt)
#pragma unroll
    for (int j = 0; j < 8; ++j)
      ob[(dt * 8 + j) * 64] = packh2(o[dt][2 * j], o[dt][2 * j + 1]);
  if (hi == 0)
    psum[((size_t)((nh * 16 + qt) * 2 + kh)) * 128 + w * 32 + l32] = lfr[0];
}

// ---------------- fused combine + out GEMM, 64x128 tiles ----------------------------
// R0's proven gemm_fused64 pattern adapted to the 32x32 f16 dump: per kt (= head h),
// each wave loads the 16 partial dwords of BOTH kh halves (lane>>5 picks kh), merges
// them with permlane32_swap, normalizes by 1/(lA+lB), packs bf16 into its own
// wave-private Xt rows (no Xt barrier). Per-iter barrier only drains the Wt DMA.
__global__ __launch_bounds__(256, 2) void out_gemm(const uint32_t* __restrict__ opart,
                                                   const float* __restrict__ psum,
                                                   const uint16_t* __restrict__ Wb,
                                                   const float* __restrict__ bias,
                                                   float* __restrict__ out) {
  __shared__ uint16_t Xt[64 * 64];       // single buffer, wave-private rows
  __shared__ uint16_t Wt[2][128 * 64];   // dbuf, gl_lds16-staged
  const int t = threadIdx.x, w = t >> 6, lane = t & 63, quad = lane >> 4, l16 = lane & 15;
  const int mblk = blockIdx.x, obk = blockIdx.y;
  const int nrow = mblk >> 5, qt_src = (mblk & 31) >> 1;
  const int m0 = mblk * 64, o0 = obk * 128;
  const int w_src = (mblk & 1) * 2 + (w >> 1);   // source flash wave for this wave's rows
  const int kh_l = lane >> 5;                    // which kh half this lane loads
  const int hi_l = (lane >> 4) & 1;              // source hi (d-offset +4)
  const int l32s = (w & 1) * 16 + (lane & 15);   // source l32 (q within flash wave)
  const int src_lane = kh_l * 0 + hi_l * 32 + l32s;  // lane within flash wave dump
  const int srow = lane >> 3, sc8 = (lane & 7) ^ (lane >> 3);

  floatx4 acc[8];
#pragma unroll
  for (int j = 0; j < 8; ++j) acc[j] = floatx4{0.f, 0.f, 0.f, 0.f};

  uint32_t va[16];
  float lp;

  auto issue_loads = [&](int h) {
    int nh2 = nrow * 16 + h;
    size_t tb = (size_t)((nh2 * 16 + qt_src) * 2 + kh_l);
    const uint32_t* pa = opart + (tb * 4 + w_src) * 1024 + src_lane;
#pragma unroll
    for (int k = 0; k < 16; ++k) va[k] = pa[k * 64];
    lp = psum[tb * 128 + w_src * 32 + l32s];
  };

  auto pack_write = [&]() {
    // merge l across kh halves (lane pairs ell, ell^32 hold the two halves)
    uint32_t lx = __builtin_bit_cast(uint32_t, lp), ly = lx;
    pl32(lx, ly);
    float lpart = __builtin_bit_cast(float, (lane < 32) ? ly : lx);
    float inv = __builtin_amdgcn_rcpf(lp + lpart);
    const int ra = w * 16 + (lane & 15);
    const int rsw = ra & 7;
#pragma unroll
    for (int k = 0; k < 16; ++k) {
      const int dt = k >> 3, j = k & 7;
      uint32_t own = va[k], x = own, y = own;
      pl32(x, y);
      uint32_t part = (lane < 32) ? y : x;
      union { uint32_t u; _Float16 h[2]; } um, up;
      um.u = own; up.u = part;
      float v0 = ((float)um.h[0] + (float)up.h[0]) * inv;
      float v1 = ((float)um.h[1] + (float)up.h[1]) * inv;
      const int d0t = (j & 1) * 2 + (j >> 1) * 8;  // j -> {0,2,8,10,16,18,24,26}
      const int d = dt * 32 + d0t + 4 * hi_l;
      if (lane < 32)
        *(uint32_t*)(&Xt[ra * 64 + ((d >> 3) ^ rsw) * 8 + (d & 7)]) = pack2(v0, v1);
    }
  };

  auto dma_w = [&](int buf, int kt) {
#pragma unroll
    for (int i = 0; i < 4; ++i) {
      int r0 = w * 32 + i * 8;
      gl_lds16(Wb + (size_t)(o0 + r0 + srow) * 1024 + kt * 64 + sc8 * 8, &Wt[buf][r0 * 64]);
    }
  };

  issue_loads(0);
  pack_write();
  dma_w(0, 0);

  for (int kt = 0; kt < 16; ++kt) {
    const int cur = kt & 1;
    __syncthreads();  // Wt[cur] DMA drained; prev-iter Wt reads complete
    if (kt + 1 < 16) {
      issue_loads(kt + 1);   // global loads in flight during MFMA below
      dma_w(cur ^ 1, kt + 1);
    }
#pragma unroll
    for (int kc = 0; kc < 2; ++kc) {
      int ra = w * 16 + l16;
      short8 a = *(const short8*)(&Xt[ra * 64 + ((kc * 4 + quad) ^ (ra & 7)) * 8]);
#pragma unroll
      for (int nf = 0; nf < 8; ++nf) {
        int rb = nf * 16 + l16;
        short8 b = *(const short8*)(&Wt[cur][rb * 64 + ((kc * 4 + quad) ^ (rb & 7)) * 8]);
        acc[nf] = __builtin_amdgcn_mfma_f32_16x16x32_bf16(a, b, acc[nf], 0, 0, 0);
      }
    }
    if (kt + 1 < 16) pack_write();  // same-wave LDS ordering: after this iter's a-reads
  }

#pragma unroll
  for (int nf = 0; nf < 8; ++nf) {
    float bv = bias[o0 + nf * 16 + l16];
#pragma unroll
    for (int r = 0; r < 4; ++r)
      out[(size_t)(m0 + w * 16 + quad * 4 + r) * 1024 + o0 + nf * 16 + l16] = acc[nf][r] + bv;
  }
}

extern "C" void kernel_launch(void* const* d_in, const int* in_sizes, int n_in,
                              void* d_out, int out_size, void* d_ws, size_t ws_size,
                              hipStream_t stream) {
  const float* values = (const float*)d_in[0];
  const float* keys   = (const float*)d_in[1];
  const float* query  = (const float*)d_in[2];
  const float* Wv     = (const float*)d_in[3];
  const float* Wk     = (const float*)d_in[4];
  const float* Wq     = (const float*)d_in[5];
  const float* Wout   = (const float*)d_in[6];
  const float* bout   = (const float*)d_in[7];
  float* out = (float*)d_out;
  (void)ws_size;

  uint16_t* ws  = (uint16_t*)d_ws;
  uint16_t* qp  = ws;                                // 8 MB bf16 [nh][l][d]
  uint16_t* kp  = ws + (size_t)4194304;              // 8 MB bf16 [nh][l][d]
  uint16_t* vp  = ws + (size_t)8388608;              // 8 MB f16  [nh][d][l]
  uint16_t* wbf = ws + (size_t)12582912;             // 2 MB bf16 Wout
  uint32_t* opart = (uint32_t*)(ws + (size_t)13631488);        // 16 MB f16-pair partial O
  float* psum = (float*)(ws + (size_t)13631488 + 8388608);     // 0.5 MB f32 partial l

  prep_kernel<<<dim3(1024), dim3(256), 0, stream>>>(values, keys, query, Wv, Wk, Wq, Wout,
                                                    qp, kp, vp, wbf);
  flash_kernel<<<dim3(32, 16, 2), dim3(256), 0, stream>>>(qp, kp, vp, opart, psum);
  out_gemm<<<dim3(64, 8), dim3(256), 0, stream>>>(opart, psum, wbf, bout, out);
}

// Round 9
// 178.633 us; speedup vs baseline: 1.0384x; 1.0384x over previous
//
#include <hip/hip_runtime.h>
#include <cstdint>

typedef __attribute__((ext_vector_type(8))) short short8;      // 8 bf16 = 4 VGPRs
typedef __attribute__((ext_vector_type(4))) float floatx4;     // 16x16 MFMA C/D frag
typedef __attribute__((ext_vector_type(16))) float floatx16;   // 32x32 MFMA C/D frag
typedef __attribute__((ext_vector_type(8))) _Float16 half8;    // 32x32x16 f16 A/B frag

#define DEV __device__ __forceinline__

constexpr int NB = 2, Lseq = 2048, NH = 16, HD = 64, EMB = 1024;
// fold softmax scale (1/sqrt(1024)) and log2(e) into Wq so flash uses exp2
constexpr float QSCALE = 0.03125f * 1.4426950408889634f;

// pack two f32 -> two bf16 in one dword (round-half-up via bias, then v_perm)
DEV uint32_t pack2(float lo, float hi) {
  uint32_t a = __builtin_bit_cast(uint32_t, lo) + 0x8000u;
  uint32_t b = __builtin_bit_cast(uint32_t, hi) + 0x8000u;
  return __builtin_amdgcn_perm(b, a, 0x07060302);
}

DEV uint32_t packh2(float lo, float hi) {  // two f32 -> packed f16 dword
  return __builtin_bit_cast(uint32_t, __builtin_amdgcn_cvt_pkrtz(lo, hi));
}

DEV void gl_lds16(const void* g, void* l) {  // async global->LDS, 16B/lane
  __builtin_amdgcn_global_load_lds((const __attribute__((address_space(1))) void*)g,
                                   (__attribute__((address_space(3))) void*)l, 16, 0, 0);
}

// half-wave exchange: after call, x = [x_lo, y_lo], y = [x_hi, y_hi] (lane blocks of 32)
DEV void pl32(uint32_t& x, uint32_t& y) {
  typedef __attribute__((ext_vector_type(2))) unsigned int uint2v;
  uint2v r = __builtin_amdgcn_permlane32_swap(x, y, false, false);
  x = r[0];
  y = r[1];
}

// load 8 consecutive f32, scale, convert to a bf16 MFMA frag chunk
DEV short8 ld8bf(const float* p, float sc) {
  float4 u = *(const float4*)p;
  float4 v = *(const float4*)(p + 4);
  union { short8 s; uint32_t d[4]; } r;
  r.d[0] = pack2(u.x * sc, u.y * sc);
  r.d[1] = pack2(u.z * sc, u.w * sc);
  r.d[2] = pack2(v.x * sc, v.y * sc);
  r.d[3] = pack2(v.z * sc, v.w * sc);
  return r.s;
}

// ---------------- prep: Q/K/V projections (MFMA, LDS-free) + Wout cvt ----------------
__global__ __launch_bounds__(256) void prep_kernel(
    const float* __restrict__ values, const float* __restrict__ keysrc,
    const float* __restrict__ query, const float* __restrict__ Wv,
    const float* __restrict__ Wk, const float* __restrict__ Wq,
    const float* __restrict__ Wout,
    uint16_t* __restrict__ qp, uint16_t* __restrict__ kp,
    uint16_t* __restrict__ vp, uint16_t* __restrict__ wbf) {
  const int t = threadIdx.x, w = t >> 6, lane = t & 63;
  const int quad = lane >> 4, l16 = lane & 15;
  const int wid = blockIdx.x * 4 + w;
  const int mat = wid >> 10, sub = wid & 1023;

  if (mat == 3) {  // Wout f32 -> bf16
#pragma unroll
    for (int i = 0; i < 4; ++i) {
      int idx = sub * 256 + i * 64 + lane;
      float4 v = ((const float4*)Wout)[idx];
      uint2 p;
      p.x = pack2(v.x, v.y);
      p.y = pack2(v.z, v.w);
      ((uint2*)wbf)[idx] = p;
    }
    return;
  }

  floatx4 c[4][4];
#pragma unroll
  for (int i = 0; i < 4; ++i)
#pragma unroll
    for (int j = 0; j < 4; ++j) c[i][j] = floatx4{0.f, 0.f, 0.f, 0.f};

  if (mat < 2) {
    const float* src = mat ? keysrc : query;
    const float* W   = mat ? Wk : Wq;
    const float asc  = mat ? 1.f : QSCALE;
    uint16_t* dst    = mat ? kp : qp;
    const int R0 = sub * 64;
    short8 a[4][2], b[4][2];
#pragma unroll
    for (int dc = 0; dc < 2; ++dc) {
#pragma unroll
      for (int f = 0; f < 4; ++f) {
        a[f][dc] = ld8bf(W + (size_t)(f * 16 + l16) * 64 + dc * 32 + quad * 8, asc);
        b[f][dc] = ld8bf(src + (size_t)(R0 + f * 16 + l16) * 64 + dc * 32 + quad * 8, 1.f);
      }
    }
#pragma unroll
    for (int dc = 0; dc < 2; ++dc)
#pragma unroll
      for (int mf = 0; mf < 4; ++mf)
#pragma unroll
        for (int nf = 0; nf < 4; ++nf)
          c[mf][nf] = __builtin_amdgcn_mfma_f32_16x16x32_bf16(a[mf][dc], b[nf][dc], c[mf][nf], 0, 0, 0);
#pragma unroll
    for (int nf = 0; nf < 4; ++nf) {
      int r = R0 + nf * 16 + l16;
      int h = r & 15, l = (r >> 4) & 2047, n = r >> 15;
      uint16_t* drow = dst + ((size_t)(n * 16 + h) * 2048 + l) * 64;
#pragma unroll
      for (int mf = 0; mf < 4; ++mf) {
        uint2 pk;
        pk.x = pack2(c[mf][nf][0], c[mf][nf][1]);
        pk.y = pack2(c[mf][nf][2], c[mf][nf][3]);
        *(uint2*)(drow + mf * 16 + quad * 4) = pk;
      }
    }
  } else {
    const int nh = sub >> 5, L0 = (sub & 31) * 64;
    const int n = nh >> 4, h = nh & 15;
    short8 a[4][2], b[4][2];
#pragma unroll
    for (int dc = 0; dc < 2; ++dc) {
#pragma unroll
      for (int f = 0; f < 4; ++f) {
        a[f][dc] = ld8bf(values + (size_t)(n * 2048 + L0 + f * 16 + l16) * 1024 + h * 64 + dc * 32 + quad * 8, 1.f);
        b[f][dc] = ld8bf(Wv + (size_t)(f * 16 + l16) * 64 + dc * 32 + quad * 8, 1.f);
      }
    }
#pragma unroll
    for (int dc = 0; dc < 2; ++dc)
#pragma unroll
      for (int mf = 0; mf < 4; ++mf)
#pragma unroll
        for (int nf = 0; nf < 4; ++nf)
          c[mf][nf] = __builtin_amdgcn_mfma_f32_16x16x32_bf16(a[mf][dc], b[nf][dc], c[mf][nf], 0, 0, 0);
#pragma unroll
    for (int nf = 0; nf < 4; ++nf) {
      int d = nf * 16 + l16;
      uint16_t* drow = vp + ((size_t)nh * 64 + d) * 2048 + L0;
#pragma unroll
      for (int mf = 0; mf < 4; ++mf) {
        uint2 pk;
        pk.x = packh2(c[mf][nf][0], c[mf][nf][1]);
        pk.y = packh2(c[mf][nf][2], c[mf][nf][3]);
        *(uint2*)(drow + mf * 16 + quad * 4) = pk;
      }
    }
  }
}

// ---------------- Flash attention: 32x32 MFMA + kh-split = 16 waves/CU ---------------
// R8 verbatim (measured 46.5 us): 32x32 math (160 MFMA-cyc per 32q*64key, conflict-
// free b128 LDS reads) at R0's occupancy (kh=2 -> 4096 waves = 16/CU, 4 blocks/CU,
// 2-buf + __syncthreads). Dumps unnormalized O^T (f16 pairs) + per-q l partials.
__global__ __launch_bounds__(256, 4) void flash_kernel(const uint16_t* __restrict__ qp,
                                                       const uint16_t* __restrict__ kp,
                                                       const uint16_t* __restrict__ vp,
                                                       uint32_t* __restrict__ opart,
                                                       float* __restrict__ psum) {
  constexpr int kbn = 16;
  __shared__ uint16_t Kt[2][64 * 64];    // swizzled [key][d] bf16
  __shared__ uint16_t Vt[2][64 * 64];    // swizzled [d][key] f16
  const int t = threadIdx.x;
  const int w = t >> 6, lane = t & 63, hi = lane >> 5, l32 = lane & 31;
  const int nh = blockIdx.x, qt = blockIdx.y, kh = blockIdx.z;
  const int q0w = qt * 128 + w * 32;     // 32 q-rows per wave
  const uint16_t* Qb = qp + (size_t)nh * Lseq * HD;
  const uint16_t* Kb = kp + (size_t)nh * Lseq * HD + (size_t)kh * 1024 * 64;
  const uint16_t* Vb = vp + (size_t)nh * HD * Lseq;
  const int vcol0 = kh * 1024;
  const int srow = lane >> 3, sc8 = (lane & 7) ^ (lane >> 3);  // staging swizzle base

  // Q B-frags (32x32x16: lane holds B[k=hi*8+i][col=l32], k = d within dc-slice)
  short8 bq[4];
#pragma unroll
  for (int dc = 0; dc < 4; ++dc)
    bq[dc] = *(const short8*)(Qb + (size_t)(q0w + l32) * 64 + dc * 16 + hi * 8);

  floatx16 o[2], lfr;   // O^T frags (dt=0,1) + ones-MFMA l accumulator
#pragma unroll
  for (int r = 0; r < 16; ++r) { o[0][r] = 0.f; o[1][r] = 0.f; lfr[r] = 0.f; }
  const _Float16 one = (_Float16)1.0f;
  const half8 vones = {one, one, one, one, one, one, one, one};

  auto stage = [&](int tile, int buf) {  // 4 DMA instrs/wave
#pragma unroll
    for (int i = 0; i < 2; ++i) {
      int r0 = w * 16 + i * 8;
      int sc = sc8 ^ ((w * 2 + i) & 3);  // (row>>3)&3 for rows r0..r0+7
      gl_lds16(Kb + (size_t)tile * 4096 + (r0 + srow) * 64 + sc * 8, &Kt[buf][r0 * 64]);
      gl_lds16(Vb + (size_t)(r0 + srow) * Lseq + vcol0 + tile * 64 + sc * 8, &Vt[buf][r0 * 64]);
    }
  };

  stage(0, 0);

  for (int kb = 0; kb < kbn; ++kb) {
    __syncthreads();
    const int cur = kb & 1;
    if (kb + 1 < kbn) stage(kb + 1, cur ^ 1);

#pragma unroll
    for (int kt = 0; kt < 2; ++kt) {
      // S^T(32keys x 32q) = K_tile · Q^T, K=16 per step over d=64
      floatx16 s;
#pragma unroll
      for (int r = 0; r < 16; ++r) s[r] = 0.f;
      const int krow = kt * 32 + l32;
      const int ksw = (krow & 7) ^ ((krow >> 3) & 3);
#pragma unroll
      for (int dc = 0; dc < 4; ++dc) {
        short8 ak = *(const short8*)(&Kt[cur][krow * 64 + (((dc << 1) | hi) ^ ksw) * 8]);
        s = __builtin_amdgcn_mfma_f32_32x32x16_bf16(ak, bq[dc], s, 0, 0, 0);
      }
      // p = exp2(s); repack to two 16-key B-frags via cvt_pkrtz + permlane32_swap.
      uint32_t a0 = packh2(__builtin_amdgcn_exp2f(s[0]), __builtin_amdgcn_exp2f(s[1]));
      uint32_t a1 = packh2(__builtin_amdgcn_exp2f(s[2]), __builtin_amdgcn_exp2f(s[3]));
      uint32_t b0 = packh2(__builtin_amdgcn_exp2f(s[4]), __builtin_amdgcn_exp2f(s[5]));
      uint32_t b1 = packh2(__builtin_amdgcn_exp2f(s[6]), __builtin_amdgcn_exp2f(s[7]));
      uint32_t c0 = packh2(__builtin_amdgcn_exp2f(s[8]), __builtin_amdgcn_exp2f(s[9]));
      uint32_t c1 = packh2(__builtin_amdgcn_exp2f(s[10]), __builtin_amdgcn_exp2f(s[11]));
      uint32_t d0 = packh2(__builtin_amdgcn_exp2f(s[12]), __builtin_amdgcn_exp2f(s[13]));
      uint32_t d1 = packh2(__builtin_amdgcn_exp2f(s[14]), __builtin_amdgcn_exp2f(s[15]));
      pl32(a0, b0); pl32(a1, b1); pl32(c0, d0); pl32(c1, d1);
      union { half8 h; uint32_t u[4]; } f0, f1;
      f0.u[0] = a0; f0.u[1] = a1; f0.u[2] = b0; f0.u[3] = b1;  // keys kt*32 + 0..15
      f1.u[0] = c0; f1.u[1] = c1; f1.u[2] = d0; f1.u[3] = d1;  // keys kt*32 + 16..31

      lfr = __builtin_amdgcn_mfma_f32_32x32x16_f16(vones, f0.h, lfr, 0, 0, 0);
      lfr = __builtin_amdgcn_mfma_f32_32x32x16_f16(vones, f1.h, lfr, 0, 0, 0);

      // O^T += V^T · P
#pragma unroll
      for (int dt = 0; dt < 2; ++dt) {
        const int vrow = dt * 32 + l32;
        const int vsw = (vrow & 7) ^ ((vrow >> 3) & 3);
        half8 av0 = *(const half8*)(&Vt[cur][vrow * 64 + ((kt * 4 + hi) ^ vsw) * 8]);
        o[dt] = __builtin_amdgcn_mfma_f32_32x32x16_f16(av0, f0.h, o[dt], 0, 0, 0);
        half8 av1 = *(const half8*)(&Vt[cur][vrow * 64 + ((kt * 4 + 2 + hi) ^ vsw) * 8]);
        o[dt] = __builtin_amdgcn_mfma_f32_32x32x16_f16(av1, f1.h, o[dt], 0, 0, 0);
      }
    }
  }

  // epilogue: dump raw O^T partial (f16 pairs, lane order) + l partial.
  // dword (dt*8+j) of lane = regs (2j,2j+1) = d-pair at d = dt*32 + (j>>1)*8 +
  // (j&1)*2 + 4*hi, q = q0w + l32. combine_kernel reconstructs with this formula.
  uint32_t* ob = opart + ((size_t)(((nh * 16 + qt) * 2 + kh) * 4 + w)) * 1024 + lane;
#pragma unroll
  for (int dt = 0; dt < 2; ++dt)
#pragma unroll
    for (int j = 0; j < 8; ++j)
      ob[(dt * 8 + j) * 64] = packh2(o[dt][2 * j], o[dt][2 * j + 1]);
  if (hi == 0)
    psum[((size_t)((nh * 16 + qt) * 2 + kh)) * 128 + w * 32 + l32] = lfr[0];
}

// ---------------- combine: merge kh partials -> normalized bf16 X --------------------
// Memory-bound bridge (~24.5 MB traffic). Per (nh,qt) block: merge the two kh f16
// partials + l sums in registers, transpose through 16 KB swizzled LDS, write X rows
// as 128B-contiguous chunks. Layout formulas identical to R8's (passing) fused gemm.
__global__ __launch_bounds__(256) void combine_kernel(const uint32_t* __restrict__ opart,
                                                      const float* __restrict__ psum,
                                                      uint16_t* __restrict__ xg) {
  __shared__ uint32_t Xs[128 * 32];      // [q_local][d_pair], 16B-chunk XOR swizzle
  const int t = threadIdx.x, w = t >> 6, lane = t & 63;
  const int hi = lane >> 5, l32 = lane & 31;
  const int nh = blockIdx.x, qt = blockIdx.y;
  const size_t tb0 = (size_t)((nh * 16 + qt) * 2);
  const uint32_t* pa0 = opart + (tb0 * 4 + w) * 1024 + lane;
  const uint32_t* pa1 = opart + ((tb0 + 1) * 4 + w) * 1024 + lane;
  const float l0 = psum[tb0 * 128 + w * 32 + l32];
  const float l1 = psum[(tb0 + 1) * 128 + w * 32 + l32];
  const float inv = __builtin_amdgcn_rcpf(l0 + l1);
  const int ql = w * 32 + l32;           // local q row 0..127

#pragma unroll
  for (int k = 0; k < 16; ++k) {
    const int dt = k >> 3, j = k & 7;
    union { uint32_t u; _Float16 h[2]; } u0, u1;
    u0.u = pa0[k * 64];
    u1.u = pa1[k * 64];
    float v0 = ((float)u0.h[0] + (float)u1.h[0]) * inv;
    float v1 = ((float)u0.h[1] + (float)u1.h[1]) * inv;
    const int d = dt * 32 + (j >> 1) * 8 + (j & 1) * 2 + 4 * hi;  // even
    Xs[ql * 32 + ((d >> 1) ^ ((ql & 7) << 2))] = pack2(v0, v1);
  }
  __syncthreads();

  const int nn = nh >> 4, h = nh & 15;
#pragma unroll
  for (int pass = 0; pass < 2; ++pass) {
    int row = pass * 64 + (t >> 2), l4 = t & 3;   // 64 rows/pass, 4 lanes x 16B per row
    uint4 v = *(const uint4*)(&Xs[row * 32 + ((l4 * 8) ^ ((row & 7) << 2))]);
    uint4 v2 = *(const uint4*)(&Xs[row * 32 + (((l4 * 8 + 4)) ^ ((row & 7) << 2))]);
    uint16_t* xr = xg + ((size_t)(nn * 2048 + qt * 128 + row)) * 1024 + h * 64 + l4 * 16;
    *(uint4*)xr = v;
    *(uint4*)(xr + 8) = v2;
  }
}

// ---------------- out GEMM: out = X @ Wout^T + bias, 64x128 tiles -------------------
// R5/R7 clean version verbatim (decomposition-measured ~27.5 us). Counted-vmcnt
// 3-buffer schedule (6 DMAs/tile/wave -> vmcnt(6)). Grid (x=64 mblk, y=8 obk):
// linear%8 = mblk%8 -> all 8 obk sharers of an X slab on one XCD.
__global__ __launch_bounds__(256, 2) void out_gemm(const uint16_t* __restrict__ Xg,
                                                   const uint16_t* __restrict__ Wb,
                                                   const float* __restrict__ bias,
                                                   float* __restrict__ out) {
  __shared__ uint16_t Xt[3][64 * 64];
  __shared__ uint16_t Wt[3][128 * 64];
  const int t = threadIdx.x, w = t >> 6, lane = t & 63, quad = lane >> 4, l16 = lane & 15;
  const int m0 = blockIdx.x * 64, o0 = blockIdx.y * 128;
  const int srow = lane >> 3, sc8 = (lane & 7) ^ (lane >> 3);

  floatx4 acc[8];
#pragma unroll
  for (int j = 0; j < 8; ++j) acc[j] = floatx4{0.f, 0.f, 0.f, 0.f};

  auto stage = [&](int buf, int kt) {  // 6 DMA instrs/wave
#pragma unroll
    for (int i = 0; i < 2; ++i) {   // X: 16 rows/wave
      int r0 = w * 16 + i * 8;
      gl_lds16(Xg + (size_t)(m0 + r0 + srow) * 1024 + kt * 64 + sc8 * 8, &Xt[buf][r0 * 64]);
    }
#pragma unroll
    for (int i = 0; i < 4; ++i) {   // W: 32 rows/wave
      int r0 = w * 32 + i * 8;
      gl_lds16(Wb + (size_t)(o0 + r0 + srow) * 1024 + kt * 64 + sc8 * 8, &Wt[buf][r0 * 64]);
    }
  };

  stage(0, 0);
  stage(1, 1);

  int cur = 0;
  for (int kt = 0; kt < 16; ++kt) {
    if (kt + 1 < 16) asm volatile("s_waitcnt vmcnt(6)" ::: "memory");
    else             asm volatile("s_waitcnt vmcnt(0)" ::: "memory");
    __builtin_amdgcn_s_barrier();
    if (kt + 2 < 16) {
      int tgt = cur + 2; if (tgt >= 3) tgt -= 3;
      stage(tgt, kt + 2);
    }
#pragma unroll
    for (int kc = 0; kc < 2; ++kc) {
      int ra = w * 16 + l16;
      short8 a = *(const short8*)(&Xt[cur][ra * 64 + ((kc * 4 + quad) ^ (ra & 7)) * 8]);
#pragma unroll
      for (int nf = 0; nf < 8; ++nf) {
        int rb = nf * 16 + l16;
        short8 b = *(const short8*)(&Wt[cur][rb * 64 + ((kc * 4 + quad) ^ (rb & 7)) * 8]);
        acc[nf] = __builtin_amdgcn_mfma_f32_16x16x32_bf16(a, b, acc[nf], 0, 0, 0);
      }
    }
    asm volatile("s_waitcnt lgkmcnt(0)" ::: "memory");
    cur = (cur + 1 == 3) ? 0 : cur + 1;
  }

#pragma unroll
  for (int nf = 0; nf < 8; ++nf) {
    float bv = bias[o0 + nf * 16 + l16];
#pragma unroll
    for (int r = 0; r < 4; ++r)
      out[(size_t)(m0 + w * 16 + quad * 4 + r) * 1024 + o0 + nf * 16 + l16] = acc[nf][r] + bv;
  }
}

extern "C" void kernel_launch(void* const* d_in, const int* in_sizes, int n_in,
                              void* d_out, int out_size, void* d_ws, size_t ws_size,
                              hipStream_t stream) {
  const float* values = (const float*)d_in[0];
  const float* keys   = (const float*)d_in[1];
  const float* query  = (const float*)d_in[2];
  const float* Wv     = (const float*)d_in[3];
  const float* Wk     = (const float*)d_in[4];
  const float* Wq     = (const float*)d_in[5];
  const float* Wout   = (const float*)d_in[6];
  const float* bout   = (const float*)d_in[7];
  float* out = (float*)d_out;
  (void)ws_size;

  uint16_t* ws  = (uint16_t*)d_ws;
  uint16_t* qp  = ws;                                // 8 MB bf16 [nh][l][d]
  uint16_t* kp  = ws + (size_t)4194304;              // 8 MB bf16 [nh][l][d]
  uint16_t* vp  = ws + (size_t)8388608;              // 8 MB f16  [nh][d][l]
  uint16_t* wbf = ws + (size_t)12582912;             // 2 MB bf16 Wout
  uint32_t* opart = (uint32_t*)(ws + (size_t)13631488);        // 16 MB f16-pair partial O
  float* psum = (float*)(ws + (size_t)22020096);               // 0.5 MB f32 partial l
  uint16_t* xp  = ws + (size_t)22282240;             // 8 MB bf16 X = normalized attn out

  prep_kernel<<<dim3(1024), dim3(256), 0, stream>>>(values, keys, query, Wv, Wk, Wq, Wout,
                                                    qp, kp, vp, wbf);
  flash_kernel<<<dim3(32, 16, 2), dim3(256), 0, stream>>>(qp, kp, vp, opart, psum);
  combine_kernel<<<dim3(32, 16), dim3(256), 0, stream>>>(opart, psum, xp);
  out_gemm<<<dim3(64, 8), dim3(256), 0, stream>>>(xp, wbf, bout, out);
}

// Round 10
// 173.175 us; speedup vs baseline: 1.0711x; 1.0315x over previous
//
#include <hip/hip_runtime.h>
#include <cstdint>

typedef __attribute__((ext_vector_type(8))) short short8;      // 8 bf16 = 4 VGPRs
typedef __attribute__((ext_vector_type(4))) float floatx4;     // 16x16 MFMA C/D frag
typedef __attribute__((ext_vector_type(16))) float floatx16;   // 32x32 MFMA C/D frag
typedef __attribute__((ext_vector_type(8))) _Float16 half8;    // 32x32x16 f16 A/B frag

#define DEV __device__ __forceinline__

constexpr int NB = 2, Lseq = 2048, NH = 16, HD = 64, EMB = 1024;
// fold softmax scale (1/sqrt(1024)) and log2(e) into Wq so flash uses exp2
constexpr float QSCALE = 0.03125f * 1.4426950408889634f;

// pack two f32 -> two bf16 in one dword (round-half-up via bias, then v_perm)
DEV uint32_t pack2(float lo, float hi) {
  uint32_t a = __builtin_bit_cast(uint32_t, lo) + 0x8000u;
  uint32_t b = __builtin_bit_cast(uint32_t, hi) + 0x8000u;
  return __builtin_amdgcn_perm(b, a, 0x07060302);
}

DEV uint32_t packh2(float lo, float hi) {  // two f32 -> packed f16 dword
  return __builtin_bit_cast(uint32_t, __builtin_amdgcn_cvt_pkrtz(lo, hi));
}

DEV void gl_lds16(const void* g, void* l) {  // async global->LDS, 16B/lane
  __builtin_amdgcn_global_load_lds((const __attribute__((address_space(1))) void*)g,
                                   (__attribute__((address_space(3))) void*)l, 16, 0, 0);
}

// half-wave exchange: after call, x = [x_lo, y_lo], y = [x_hi, y_hi] (lane blocks of 32)
DEV void pl32(uint32_t& x, uint32_t& y) {
  typedef __attribute__((ext_vector_type(2))) unsigned int uint2v;
  uint2v r = __builtin_amdgcn_permlane32_swap(x, y, false, false);
  x = r[0];
  y = r[1];
}

// load 8 consecutive f32, scale, convert to a bf16 MFMA frag chunk
DEV short8 ld8bf(const float* p, float sc) {
  float4 u = *(const float4*)p;
  float4 v = *(const float4*)(p + 4);
  union { short8 s; uint32_t d[4]; } r;
  r.d[0] = pack2(u.x * sc, u.y * sc);
  r.d[1] = pack2(u.z * sc, u.w * sc);
  r.d[2] = pack2(v.x * sc, v.y * sc);
  r.d[3] = pack2(v.z * sc, v.w * sc);
  return r.s;
}

// ---------------- prep: Q/K/V projections (MFMA, LDS-free) + Wout cvt ----------------
__global__ __launch_bounds__(256) void prep_kernel(
    const float* __restrict__ values, const float* __restrict__ keysrc,
    const float* __restrict__ query, const float* __restrict__ Wv,
    const float* __restrict__ Wk, const float* __restrict__ Wq,
    const float* __restrict__ Wout,
    uint16_t* __restrict__ qp, uint16_t* __restrict__ kp,
    uint16_t* __restrict__ vp, uint16_t* __restrict__ wbf) {
  const int t = threadIdx.x, w = t >> 6, lane = t & 63;
  const int quad = lane >> 4, l16 = lane & 15;
  const int wid = blockIdx.x * 4 + w;
  const int mat = wid >> 10, sub = wid & 1023;

  if (mat == 3) {  // Wout f32 -> bf16
#pragma unroll
    for (int i = 0; i < 4; ++i) {
      int idx = sub * 256 + i * 64 + lane;
      float4 v = ((const float4*)Wout)[idx];
      uint2 p;
      p.x = pack2(v.x, v.y);
      p.y = pack2(v.z, v.w);
      ((uint2*)wbf)[idx] = p;
    }
    return;
  }

  floatx4 c[4][4];
#pragma unroll
  for (int i = 0; i < 4; ++i)
#pragma unroll
    for (int j = 0; j < 4; ++j) c[i][j] = floatx4{0.f, 0.f, 0.f, 0.f};

  if (mat < 2) {
    const float* src = mat ? keysrc : query;
    const float* W   = mat ? Wk : Wq;
    const float asc  = mat ? 1.f : QSCALE;
    uint16_t* dst    = mat ? kp : qp;
    const int R0 = sub * 64;
    short8 a[4][2], b[4][2];
#pragma unroll
    for (int dc = 0; dc < 2; ++dc) {
#pragma unroll
      for (int f = 0; f < 4; ++f) {
        a[f][dc] = ld8bf(W + (size_t)(f * 16 + l16) * 64 + dc * 32 + quad * 8, asc);
        b[f][dc] = ld8bf(src + (size_t)(R0 + f * 16 + l16) * 64 + dc * 32 + quad * 8, 1.f);
      }
    }
#pragma unroll
    for (int dc = 0; dc < 2; ++dc)
#pragma unroll
      for (int mf = 0; mf < 4; ++mf)
#pragma unroll
        for (int nf = 0; nf < 4; ++nf)
          c[mf][nf] = __builtin_amdgcn_mfma_f32_16x16x32_bf16(a[mf][dc], b[nf][dc], c[mf][nf], 0, 0, 0);
#pragma unroll
    for (int nf = 0; nf < 4; ++nf) {
      int r = R0 + nf * 16 + l16;
      int h = r & 15, l = (r >> 4) & 2047, n = r >> 15;
      uint16_t* drow = dst + ((size_t)(n * 16 + h) * 2048 + l) * 64;
#pragma unroll
      for (int mf = 0; mf < 4; ++mf) {
        uint2 pk;
        pk.x = pack2(c[mf][nf][0], c[mf][nf][1]);
        pk.y = pack2(c[mf][nf][2], c[mf][nf][3]);
        *(uint2*)(drow + mf * 16 + quad * 4) = pk;
      }
    }
  } else {
    const int nh = sub >> 5, L0 = (sub & 31) * 64;
    const int n = nh >> 4, h = nh & 15;
    short8 a[4][2], b[4][2];
#pragma unroll
    for (int dc = 0; dc < 2; ++dc) {
#pragma unroll
      for (int f = 0; f < 4; ++f) {
        a[f][dc] = ld8bf(values + (size_t)(n * 2048 + L0 + f * 16 + l16) * 1024 + h * 64 + dc * 32 + quad * 8, 1.f);
        b[f][dc] = ld8bf(Wv + (size_t)(f * 16 + l16) * 64 + dc * 32 + quad * 8, 1.f);
      }
    }
#pragma unroll
    for (int dc = 0; dc < 2; ++dc)
#pragma unroll
      for (int mf = 0; mf < 4; ++mf)
#pragma unroll
        for (int nf = 0; nf < 4; ++nf)
          c[mf][nf] = __builtin_amdgcn_mfma_f32_16x16x32_bf16(a[mf][dc], b[nf][dc], c[mf][nf], 0, 0, 0);
#pragma unroll
    for (int nf = 0; nf < 4; ++nf) {
      int d = nf * 16 + l16;
      uint16_t* drow = vp + ((size_t)nh * 64 + d) * 2048 + L0;
#pragma unroll
      for (int mf = 0; mf < 4; ++mf) {
        uint2 pk;
        pk.x = packh2(c[mf][nf][0], c[mf][nf][1]);
        pk.y = packh2(c[mf][nf][2], c[mf][nf][3]);
        *(uint2*)(drow + mf * 16 + quad * 4) = pk;
      }
    }
  }
}

// ---------------- Flash attention: 32x32 MFMA + kh-split = 16 waves/CU ---------------
// R9 structure (measured 48 us) with two pipe-time cuts:
//  (1) ones-MFMA l-accumulation (4 of 20 MFMAs/tile, 20% of the MFMA floor) replaced
//      by a 15-add VALU tree over the already-live exp registers; epilogue reduces
//      the two hi-halves with one permlane32_swap. psum format unchanged.
//  (2) s_setprio(1) around the QK and PV MFMA clusters (T5).
__global__ __launch_bounds__(256, 4) void flash_kernel(const uint16_t* __restrict__ qp,
                                                       const uint16_t* __restrict__ kp,
                                                       const uint16_t* __restrict__ vp,
                                                       uint32_t* __restrict__ opart,
                                                       float* __restrict__ psum) {
  constexpr int kbn = 16;
  __shared__ uint16_t Kt[2][64 * 64];    // swizzled [key][d] bf16
  __shared__ uint16_t Vt[2][64 * 64];    // swizzled [d][key] f16
  const int t = threadIdx.x;
  const int w = t >> 6, lane = t & 63, hi = lane >> 5, l32 = lane & 31;
  const int nh = blockIdx.x, qt = blockIdx.y, kh = blockIdx.z;
  const int q0w = qt * 128 + w * 32;     // 32 q-rows per wave
  const uint16_t* Qb = qp + (size_t)nh * Lseq * HD;
  const uint16_t* Kb = kp + (size_t)nh * Lseq * HD + (size_t)kh * 1024 * 64;
  const uint16_t* Vb = vp + (size_t)nh * HD * Lseq;
  const int vcol0 = kh * 1024;
  const int srow = lane >> 3, sc8 = (lane & 7) ^ (lane >> 3);  // staging swizzle base

  // Q B-frags (32x32x16: lane holds B[k=hi*8+i][col=l32], k = d within dc-slice)
  short8 bq[4];
#pragma unroll
  for (int dc = 0; dc < 4; ++dc)
    bq[dc] = *(const short8*)(Qb + (size_t)(q0w + l32) * 64 + dc * 16 + hi * 8);

  floatx16 o[2];        // O^T frags (dt=0,1)
  float lsum = 0.f;     // VALU l partial: this lane's hi-half keys, q = l32
#pragma unroll
  for (int r = 0; r < 16; ++r) { o[0][r] = 0.f; o[1][r] = 0.f; }

  auto stage = [&](int tile, int buf) {  // 4 DMA instrs/wave
#pragma unroll
    for (int i = 0; i < 2; ++i) {
      int r0 = w * 16 + i * 8;
      int sc = sc8 ^ ((w * 2 + i) & 3);  // (row>>3)&3 for rows r0..r0+7
      gl_lds16(Kb + (size_t)tile * 4096 + (r0 + srow) * 64 + sc * 8, &Kt[buf][r0 * 64]);
      gl_lds16(Vb + (size_t)(r0 + srow) * Lseq + vcol0 + tile * 64 + sc * 8, &Vt[buf][r0 * 64]);
    }
  };

  stage(0, 0);

  for (int kb = 0; kb < kbn; ++kb) {
    __syncthreads();
    const int cur = kb & 1;
    if (kb + 1 < kbn) stage(kb + 1, cur ^ 1);

#pragma unroll
    for (int kt = 0; kt < 2; ++kt) {
      // S^T(32keys x 32q) = K_tile · Q^T, K=16 per step over d=64
      floatx16 s;
#pragma unroll
      for (int r = 0; r < 16; ++r) s[r] = 0.f;
      const int krow = kt * 32 + l32;
      const int ksw = (krow & 7) ^ ((krow >> 3) & 3);
      __builtin_amdgcn_s_setprio(1);
#pragma unroll
      for (int dc = 0; dc < 4; ++dc) {
        short8 ak = *(const short8*)(&Kt[cur][krow * 64 + (((dc << 1) | hi) ^ ksw) * 8]);
        s = __builtin_amdgcn_mfma_f32_32x32x16_bf16(ak, bq[dc], s, 0, 0, 0);
      }
      __builtin_amdgcn_s_setprio(0);

      // p = exp2(s); l partial on VALU (tree over live regs); repack to two 16-key
      // B-frags via cvt_pkrtz + permlane32_swap.
      float ex[16];
#pragma unroll
      for (int r = 0; r < 16; ++r) ex[r] = __builtin_amdgcn_exp2f(s[r]);
      float t0 = (ex[0] + ex[1]) + (ex[2] + ex[3]);
      float t1 = (ex[4] + ex[5]) + (ex[6] + ex[7]);
      float t2 = (ex[8] + ex[9]) + (ex[10] + ex[11]);
      float t3 = (ex[12] + ex[13]) + (ex[14] + ex[15]);
      lsum += (t0 + t1) + (t2 + t3);

      uint32_t a0 = packh2(ex[0], ex[1]);
      uint32_t a1 = packh2(ex[2], ex[3]);
      uint32_t b0 = packh2(ex[4], ex[5]);
      uint32_t b1 = packh2(ex[6], ex[7]);
      uint32_t c0 = packh2(ex[8], ex[9]);
      uint32_t c1 = packh2(ex[10], ex[11]);
      uint32_t d0 = packh2(ex[12], ex[13]);
      uint32_t d1 = packh2(ex[14], ex[15]);
      pl32(a0, b0); pl32(a1, b1); pl32(c0, d0); pl32(c1, d1);
      union { half8 h; uint32_t u[4]; } f0, f1;
      f0.u[0] = a0; f0.u[1] = a1; f0.u[2] = b0; f0.u[3] = b1;  // keys kt*32 + 0..15
      f1.u[0] = c0; f1.u[1] = c1; f1.u[2] = d0; f1.u[3] = d1;  // keys kt*32 + 16..31

      // O^T += V^T · P
      __builtin_amdgcn_s_setprio(1);
#pragma unroll
      for (int dt = 0; dt < 2; ++dt) {
        const int vrow = dt * 32 + l32;
        const int vsw = (vrow & 7) ^ ((vrow >> 3) & 3);
        half8 av0 = *(const half8*)(&Vt[cur][vrow * 64 + ((kt * 4 + hi) ^ vsw) * 8]);
        o[dt] = __builtin_amdgcn_mfma_f32_32x32x16_f16(av0, f0.h, o[dt], 0, 0, 0);
        half8 av1 = *(const half8*)(&Vt[cur][vrow * 64 + ((kt * 4 + 2 + hi) ^ vsw) * 8]);
        o[dt] = __builtin_amdgcn_mfma_f32_32x32x16_f16(av1, f1.h, o[dt], 0, 0, 0);
      }
      __builtin_amdgcn_s_setprio(0);
    }
  }

  // finish l: add the other hi-half's partial (lanes l32 and l32+32 share q = l32)
  {
    uint32_t sx = __builtin_bit_cast(uint32_t, lsum), sy = sx;
    pl32(sx, sy);
    float oth = __builtin_bit_cast(float, (lane < 32) ? sy : sx);
    lsum += oth;
  }

  // epilogue: dump raw O^T partial (f16 pairs, lane order) + l partial.
  // dword (dt*8+j) of lane = regs (2j,2j+1) = d-pair at d = dt*32 + (j>>1)*8 +
  // (j&1)*2 + 4*hi, q = q0w + l32. combine_kernel reconstructs with this formula.
  uint32_t* ob = opart + ((size_t)(((nh * 16 + qt) * 2 + kh) * 4 + w)) * 1024 + lane;
#pragma unroll
  for (int dt = 0; dt < 2; ++dt)
#pragma unroll
    for (int j = 0; j < 8; ++j)
      ob[(dt * 8 + j) * 64] = packh2(o[dt][2 * j], o[dt][2 * j + 1]);
  if (hi == 0)
    psum[((size_t)((nh * 16 + qt) * 2 + kh)) * 128 + w * 32 + l32] = lsum;
}

// ---------------- combine: merge kh partials -> normalized bf16 X --------------------
// (R9 verbatim.) Per (nh,qt) block: merge the two kh f16 partials + l sums in
// registers, transpose through 16 KB swizzled LDS, write X rows 128B-contiguous.
__global__ __launch_bounds__(256) void combine_kernel(const uint32_t* __restrict__ opart,
                                                      const float* __restrict__ psum,
                                                      uint16_t* __restrict__ xg) {
  __shared__ uint32_t Xs[128 * 32];      // [q_local][d_pair], 16B-chunk XOR swizzle
  const int t = threadIdx.x, w = t >> 6, lane = t & 63;
  const int hi = lane >> 5, l32 = lane & 31;
  const int nh = blockIdx.x, qt = blockIdx.y;
  const size_t tb0 = (size_t)((nh * 16 + qt) * 2);
  const uint32_t* pa0 = opart + (tb0 * 4 + w) * 1024 + lane;
  const uint32_t* pa1 = opart + ((tb0 + 1) * 4 + w) * 1024 + lane;
  const float l0 = psum[tb0 * 128 + w * 32 + l32];
  const float l1 = psum[(tb0 + 1) * 128 + w * 32 + l32];
  const float inv = __builtin_amdgcn_rcpf(l0 + l1);
  const int ql = w * 32 + l32;           // local q row 0..127

#pragma unroll
  for (int k = 0; k < 16; ++k) {
    const int dt = k >> 3, j = k & 7;
    union { uint32_t u; _Float16 h[2]; } u0, u1;
    u0.u = pa0[k * 64];
    u1.u = pa1[k * 64];
    float v0 = ((float)u0.h[0] + (float)u1.h[0]) * inv;
    float v1 = ((float)u0.h[1] + (float)u1.h[1]) * inv;
    const int d = dt * 32 + (j >> 1) * 8 + (j & 1) * 2 + 4 * hi;  // even
    Xs[ql * 32 + ((d >> 1) ^ ((ql & 7) << 2))] = pack2(v0, v1);
  }
  __syncthreads();

  const int nn = nh >> 4, h = nh & 15;
#pragma unroll
  for (int pass = 0; pass < 2; ++pass) {
    int row = pass * 64 + (t >> 2), l4 = t & 3;   // 64 rows/pass, 4 lanes x 16B per row
    uint4 v = *(const uint4*)(&Xs[row * 32 + ((l4 * 8) ^ ((row & 7) << 2))]);
    uint4 v2 = *(const uint4*)(&Xs[row * 32 + (((l4 * 8 + 4)) ^ ((row & 7) << 2))]);
    uint16_t* xr = xg + ((size_t)(nn * 2048 + qt * 128 + row)) * 1024 + h * 64 + l4 * 16;
    *(uint4*)xr = v;
    *(uint4*)(xr + 8) = v2;
  }
}

// ---------------- out GEMM: out = X @ Wout^T + bias, 64x128 tiles -------------------
// (R9 verbatim.) Counted-vmcnt 3-buffer schedule (6 DMAs/tile/wave -> vmcnt(6)).
__global__ __launch_bounds__(256, 2) void out_gemm(const uint16_t* __restrict__ Xg,
                                                   const uint16_t* __restrict__ Wb,
                                                   const float* __restrict__ bias,
                                                   float* __restrict__ out) {
  __shared__ uint16_t Xt[3][64 * 64];
  __shared__ uint16_t Wt[3][128 * 64];
  const int t = threadIdx.x, w = t >> 6, lane = t & 63, quad = lane >> 4, l16 = lane & 15;
  const int m0 = blockIdx.x * 64, o0 = blockIdx.y * 128;
  const int srow = lane >> 3, sc8 = (lane & 7) ^ (lane >> 3);

  floatx4 acc[8];
#pragma unroll
  for (int j = 0; j < 8; ++j) acc[j] = floatx4{0.f, 0.f, 0.f, 0.f};

  auto stage = [&](int buf, int kt) {  // 6 DMA instrs/wave
#pragma unroll
    for (int i = 0; i < 2; ++i) {   // X: 16 rows/wave
      int r0 = w * 16 + i * 8;
      gl_lds16(Xg + (size_t)(m0 + r0 + srow) * 1024 + kt * 64 + sc8 * 8, &Xt[buf][r0 * 64]);
    }
#pragma unroll
    for (int i = 0; i < 4; ++i) {   // W: 32 rows/wave
      int r0 = w * 32 + i * 8;
      gl_lds16(Wb + (size_t)(o0 + r0 + srow) * 1024 + kt * 64 + sc8 * 8, &Wt[buf][r0 * 64]);
    }
  };

  stage(0, 0);
  stage(1, 1);

  int cur = 0;
  for (int kt = 0; kt < 16; ++kt) {
    if (kt + 1 < 16) asm volatile("s_waitcnt vmcnt(6)" ::: "memory");
    else             asm volatile("s_waitcnt vmcnt(0)" ::: "memory");
    __builtin_amdgcn_s_barrier();
    if (kt + 2 < 16) {
      int tgt = cur + 2; if (tgt >= 3) tgt -= 3;
      stage(tgt, kt + 2);
    }
#pragma unroll
    for (int kc = 0; kc < 2; ++kc) {
      int ra = w * 16 + l16;
      short8 a = *(const short8*)(&Xt[cur][ra * 64 + ((kc * 4 + quad) ^ (ra & 7)) * 8]);
#pragma unroll
      for (int nf = 0; nf < 8; ++nf) {
        int rb = nf * 16 + l16;
        short8 b = *(const short8*)(&Wt[cur][rb * 64 + ((kc * 4 + quad) ^ (rb & 7)) * 8]);
        acc[nf] = __builtin_amdgcn_mfma_f32_16x16x32_bf16(a, b, acc[nf], 0, 0, 0);
      }
    }
    asm volatile("s_waitcnt lgkmcnt(0)" ::: "memory");
    cur = (cur + 1 == 3) ? 0 : cur + 1;
  }

#pragma unroll
  for (int nf = 0; nf < 8; ++nf) {
    float bv = bias[o0 + nf * 16 + l16];
#pragma unroll
    for (int r = 0; r < 4; ++r)
      out[(size_t)(m0 + w * 16 + quad * 4 + r) * 1024 + o0 + nf * 16 + l16] = acc[nf][r] + bv;
  }
}

extern "C" void kernel_launch(void* const* d_in, const int* in_sizes, int n_in,
                              void* d_out, int out_size, void* d_ws, size_t ws_size,
                              hipStream_t stream) {
  const float* values = (const float*)d_in[0];
  const float* keys   = (const float*)d_in[1];
  const float* query  = (const float*)d_in[2];
  const float* Wv     = (const float*)d_in[3];
  const float* Wk     = (const float*)d_in[4];
  const float* Wq     = (const float*)d_in[5];
  const float* Wout   = (const float*)d_in[6];
  const float* bout   = (const float*)d_in[7];
  float* out = (float*)d_out;
  (void)ws_size;

  uint16_t* ws  = (uint16_t*)d_ws;
  uint16_t* qp  = ws;                                // 8 MB bf16 [nh][l][d]
  uint16_t* kp  = ws + (size_t)4194304;              // 8 MB bf16 [nh][l][d]
  uint16_t* vp  = ws + (size_t)8388608;              // 8 MB f16  [nh][d][l]
  uint16_t* wbf = ws + (size_t)12582912;             // 2 MB bf16 Wout
  uint32_t* opart = (uint32_t*)(ws + (size_t)13631488);        // 16 MB f16-pair partial O
  float* psum = (float*)(ws + (size_t)22020096);               // 0.5 MB f32 partial l
  uint16_t* xp  = ws + (size_t)22282240;             // 8 MB bf16 X = normalized attn out

  prep_kernel<<<dim3(1024), dim3(256), 0, stream>>>(values, keys, query, Wv, Wk, Wq, Wout,
                                                    qp, kp, vp, wbf);
  flash_kernel<<<dim3(32, 16, 2), dim3(256), 0, stream>>>(qp, kp, vp, opart, psum);
  combine_kernel<<<dim3(32, 16), dim3(256), 0, stream>>>(opart, psum, xp);
  out_gemm<<<dim3(64, 8), dim3(256), 0, stream>>>(xp, wbf, bout, out);
}

// Round 11
// 169.978 us; speedup vs baseline: 1.0913x; 1.0188x over previous
//
#include <hip/hip_runtime.h>
#include <cstdint>

typedef __attribute__((ext_vector_type(8))) short short8;      // 8 bf16 = 4 VGPRs
typedef __attribute__((ext_vector_type(4))) float floatx4;     // 16x16 MFMA C/D frag
typedef __attribute__((ext_vector_type(16))) float floatx16;   // 32x32 MFMA C/D frag
typedef __attribute__((ext_vector_type(8))) _Float16 half8;    // 32x32x16 f16 A/B frag

#define DEV __device__ __forceinline__

constexpr int NB = 2, Lseq = 2048, NH = 16, HD = 64, EMB = 1024;
// fold softmax scale (1/sqrt(1024)) and log2(e) into Wq so flash uses exp2
constexpr float QSCALE = 0.03125f * 1.4426950408889634f;

// pack two f32 -> two bf16 in one dword (round-half-up via bias, then v_perm)
DEV uint32_t pack2(float lo, float hi) {
  uint32_t a = __builtin_bit_cast(uint32_t, lo) + 0x8000u;
  uint32_t b = __builtin_bit_cast(uint32_t, hi) + 0x8000u;
  return __builtin_amdgcn_perm(b, a, 0x07060302);
}

DEV uint32_t packh2(float lo, float hi) {  // two f32 -> packed f16 dword
  return __builtin_bit_cast(uint32_t, __builtin_amdgcn_cvt_pkrtz(lo, hi));
}

DEV void gl_lds16(const void* g, void* l) {  // async global->LDS, 16B/lane
  __builtin_amdgcn_global_load_lds((const __attribute__((address_space(1))) void*)g,
                                   (__attribute__((address_space(3))) void*)l, 16, 0, 0);
}

// half-wave exchange: after call, x = [x_lo, y_lo], y = [x_hi, y_hi] (lane blocks of 32)
DEV void pl32(uint32_t& x, uint32_t& y) {
  typedef __attribute__((ext_vector_type(2))) unsigned int uint2v;
  uint2v r = __builtin_amdgcn_permlane32_swap(x, y, false, false);
  x = r[0];
  y = r[1];
}

// load 8 consecutive f32, scale, convert to a bf16 MFMA frag chunk
DEV short8 ld8bf(const float* p, float sc) {
  float4 u = *(const float4*)p;
  float4 v = *(const float4*)(p + 4);
  union { short8 s; uint32_t d[4]; } r;
  r.d[0] = pack2(u.x * sc, u.y * sc);
  r.d[1] = pack2(u.z * sc, u.w * sc);
  r.d[2] = pack2(v.x * sc, v.y * sc);
  r.d[3] = pack2(v.z * sc, v.w * sc);
  return r.s;
}

// ---------------- prep: Q/K/V projections (MFMA, LDS-free) + Wout cvt ----------------
__global__ __launch_bounds__(256) void prep_kernel(
    const float* __restrict__ values, const float* __restrict__ keysrc,
    const float* __restrict__ query, const float* __restrict__ Wv,
    const float* __restrict__ Wk, const float* __restrict__ Wq,
    const float* __restrict__ Wout,
    uint16_t* __restrict__ qp, uint16_t* __restrict__ kp,
    uint16_t* __restrict__ vp, uint16_t* __restrict__ wbf) {
  const int t = threadIdx.x, w = t >> 6, lane = t & 63;
  const int quad = lane >> 4, l16 = lane & 15;
  const int wid = blockIdx.x * 4 + w;
  const int mat = wid >> 10, sub = wid & 1023;

  if (mat == 3) {  // Wout f32 -> bf16
#pragma unroll
    for (int i = 0; i < 4; ++i) {
      int idx = sub * 256 + i * 64 + lane;
      float4 v = ((const float4*)Wout)[idx];
      uint2 p;
      p.x = pack2(v.x, v.y);
      p.y = pack2(v.z, v.w);
      ((uint2*)wbf)[idx] = p;
    }
    return;
  }

  floatx4 c[4][4];
#pragma unroll
  for (int i = 0; i < 4; ++i)
#pragma unroll
    for (int j = 0; j < 4; ++j) c[i][j] = floatx4{0.f, 0.f, 0.f, 0.f};

  if (mat < 2) {
    const float* src = mat ? keysrc : query;
    const float* W   = mat ? Wk : Wq;
    const float asc  = mat ? 1.f : QSCALE;
    uint16_t* dst    = mat ? kp : qp;
    const int R0 = sub * 64;
    short8 a[4][2], b[4][2];
#pragma unroll
    for (int dc = 0; dc < 2; ++dc) {
#pragma unroll
      for (int f = 0; f < 4; ++f) {
        a[f][dc] = ld8bf(W + (size_t)(f * 16 + l16) * 64 + dc * 32 + quad * 8, asc);
        b[f][dc] = ld8bf(src + (size_t)(R0 + f * 16 + l16) * 64 + dc * 32 + quad * 8, 1.f);
      }
    }
#pragma unroll
    for (int dc = 0; dc < 2; ++dc)
#pragma unroll
      for (int mf = 0; mf < 4; ++mf)
#pragma unroll
        for (int nf = 0; nf < 4; ++nf)
          c[mf][nf] = __builtin_amdgcn_mfma_f32_16x16x32_bf16(a[mf][dc], b[nf][dc], c[mf][nf], 0, 0, 0);
#pragma unroll
    for (int nf = 0; nf < 4; ++nf) {
      int r = R0 + nf * 16 + l16;
      int h = r & 15, l = (r >> 4) & 2047, n = r >> 15;
      uint16_t* drow = dst + ((size_t)(n * 16 + h) * 2048 + l) * 64;
#pragma unroll
      for (int mf = 0; mf < 4; ++mf) {
        uint2 pk;
        pk.x = pack2(c[mf][nf][0], c[mf][nf][1]);
        pk.y = pack2(c[mf][nf][2], c[mf][nf][3]);
        *(uint2*)(drow + mf * 16 + quad * 4) = pk;
      }
    }
  } else {
    const int nh = sub >> 5, L0 = (sub & 31) * 64;
    const int n = nh >> 4, h = nh & 15;
    short8 a[4][2], b[4][2];
#pragma unroll
    for (int dc = 0; dc < 2; ++dc) {
#pragma unroll
      for (int f = 0; f < 4; ++f) {
        a[f][dc] = ld8bf(values + (size_t)(n * 2048 + L0 + f * 16 + l16) * 1024 + h * 64 + dc * 32 + quad * 8, 1.f);
        b[f][dc] = ld8bf(Wv + (size_t)(f * 16 + l16) * 64 + dc * 32 + quad * 8, 1.f);
      }
    }
#pragma unroll
    for (int dc = 0; dc < 2; ++dc)
#pragma unroll
      for (int mf = 0; mf < 4; ++mf)
#pragma unroll
        for (int nf = 0; nf < 4; ++nf)
          c[mf][nf] = __builtin_amdgcn_mfma_f32_16x16x32_bf16(a[mf][dc], b[nf][dc], c[mf][nf], 0, 0, 0);
#pragma unroll
    for (int nf = 0; nf < 4; ++nf) {
      int d = nf * 16 + l16;
      uint16_t* drow = vp + ((size_t)nh * 64 + d) * 2048 + L0;
#pragma unroll
      for (int mf = 0; mf < 4; ++mf) {
        uint2 pk;
        pk.x = packh2(c[mf][nf][0], c[mf][nf][1]);
        pk.y = packh2(c[mf][nf][2], c[mf][nf][3]);
        *(uint2*)(drow + mf * 16 + quad * 4) = pk;
      }
    }
  }
}

// ---------------- Flash attention: 8-wave blocks, in-block kh combine ---------------
// R10 main loop verbatim per wave (32x32 MFMA, VALU lsum, setprio, 2-buf +
// __syncthreads), but both kh halves live in ONE 512-thread block: waves 0-3 = kh0,
// 4-7 = kh1, each half with its own K/V double buffer (64 KB total, 2 blocks/CU ->
// same 16 waves/CU as R10). After the loop, kh1 waves dump f16-pair partials + l into
// LDS scratch (conflict-free [k][wave][lane] layout, reusing Kt); kh1's lockstep
// tiles mean one barrier suffices. kh0 waves merge, normalize, and write bf16 X
// directly (R6-verified store formula). Deletes the 16.9MB opart write, the combine
// kernel's 17MB read, and one launch.
__global__ __launch_bounds__(512, 2) void flash_kernel(const uint16_t* __restrict__ qp,
                                                       const uint16_t* __restrict__ kp,
                                                       const uint16_t* __restrict__ vp,
                                                       uint16_t* __restrict__ xg) {
  constexpr int kbn = 16;
  __shared__ uint16_t Kt[2][2][64 * 64];   // [kh][buf] swizzled [key][d] bf16
  __shared__ uint16_t Vt[2][2][64 * 64];   // [kh][buf] swizzled [d][key] f16
  const int t = threadIdx.x;
  const int w = t >> 6, lane = t & 63, hi = lane >> 5, l32 = lane & 31;
  const int kh = w >> 2, wq = w & 3;
  const int nh = blockIdx.x, qt = blockIdx.y;
  const int q0w = qt * 128 + wq * 32;    // 32 q-rows per wave (kh pair shares q-range)
  const uint16_t* Qb = qp + (size_t)nh * Lseq * HD;
  const uint16_t* Kb = kp + (size_t)nh * Lseq * HD + (size_t)kh * 1024 * 64;
  const uint16_t* Vb = vp + (size_t)nh * HD * Lseq;
  const int vcol0 = kh * 1024;
  const int srow = lane >> 3, sc8 = (lane & 7) ^ (lane >> 3);  // staging swizzle base

  // Q B-frags (32x32x16: lane holds B[k=hi*8+i][col=l32], k = d within dc-slice)
  short8 bq[4];
#pragma unroll
  for (int dc = 0; dc < 4; ++dc)
    bq[dc] = *(const short8*)(Qb + (size_t)(q0w + l32) * 64 + dc * 16 + hi * 8);

  floatx16 o[2];        // O^T frags (dt=0,1)
  float lsum = 0.f;     // VALU l partial
#pragma unroll
  for (int r = 0; r < 16; ++r) { o[0][r] = 0.f; o[1][r] = 0.f; }

  auto stage = [&](int tile, int buf) {  // 4 DMA instrs/wave (8 row-groups / 4 waves)
#pragma unroll
    for (int i = 0; i < 2; ++i) {
      int r0 = wq * 16 + i * 8;
      int sc = sc8 ^ ((wq * 2 + i) & 3);  // (row>>3)&3 for rows r0..r0+7
      gl_lds16(Kb + (size_t)tile * 4096 + (r0 + srow) * 64 + sc * 8, &Kt[kh][buf][r0 * 64]);
      gl_lds16(Vb + (size_t)(r0 + srow) * Lseq + vcol0 + tile * 64 + sc * 8, &Vt[kh][buf][r0 * 64]);
    }
  };

  stage(0, 0);

  for (int kb = 0; kb < kbn; ++kb) {
    __syncthreads();
    const int cur = kb & 1;
    if (kb + 1 < kbn) stage(kb + 1, cur ^ 1);

#pragma unroll
    for (int kt = 0; kt < 2; ++kt) {
      // S^T(32keys x 32q) = K_tile · Q^T, K=16 per step over d=64
      floatx16 s;
#pragma unroll
      for (int r = 0; r < 16; ++r) s[r] = 0.f;
      const int krow = kt * 32 + l32;
      const int ksw = (krow & 7) ^ ((krow >> 3) & 3);
      __builtin_amdgcn_s_setprio(1);
#pragma unroll
      for (int dc = 0; dc < 4; ++dc) {
        short8 ak = *(const short8*)(&Kt[kh][cur][krow * 64 + (((dc << 1) | hi) ^ ksw) * 8]);
        s = __builtin_amdgcn_mfma_f32_32x32x16_bf16(ak, bq[dc], s, 0, 0, 0);
      }
      __builtin_amdgcn_s_setprio(0);

      // p = exp2(s); l partial on VALU; repack to two 16-key B-frags.
      float ex[16];
#pragma unroll
      for (int r = 0; r < 16; ++r) ex[r] = __builtin_amdgcn_exp2f(s[r]);
      float t0 = (ex[0] + ex[1]) + (ex[2] + ex[3]);
      float t1 = (ex[4] + ex[5]) + (ex[6] + ex[7]);
      float t2 = (ex[8] + ex[9]) + (ex[10] + ex[11]);
      float t3 = (ex[12] + ex[13]) + (ex[14] + ex[15]);
      lsum += (t0 + t1) + (t2 + t3);

      uint32_t a0 = packh2(ex[0], ex[1]);
      uint32_t a1 = packh2(ex[2], ex[3]);
      uint32_t b0 = packh2(ex[4], ex[5]);
      uint32_t b1 = packh2(ex[6], ex[7]);
      uint32_t c0 = packh2(ex[8], ex[9]);
      uint32_t c1 = packh2(ex[10], ex[11]);
      uint32_t d0 = packh2(ex[12], ex[13]);
      uint32_t d1 = packh2(ex[14], ex[15]);
      pl32(a0, b0); pl32(a1, b1); pl32(c0, d0); pl32(c1, d1);
      union { half8 h; uint32_t u[4]; } f0, f1;
      f0.u[0] = a0; f0.u[1] = a1; f0.u[2] = b0; f0.u[3] = b1;  // keys kt*32 + 0..15
      f1.u[0] = c0; f1.u[1] = c1; f1.u[2] = d0; f1.u[3] = d1;  // keys kt*32 + 16..31

      // O^T += V^T · P
      __builtin_amdgcn_s_setprio(1);
#pragma unroll
      for (int dt = 0; dt < 2; ++dt) {
        const int vrow = dt * 32 + l32;
        const int vsw = (vrow & 7) ^ ((vrow >> 3) & 3);
        half8 av0 = *(const half8*)(&Vt[kh][cur][vrow * 64 + ((kt * 4 + hi) ^ vsw) * 8]);
        o[dt] = __builtin_amdgcn_mfma_f32_32x32x16_f16(av0, f0.h, o[dt], 0, 0, 0);
        half8 av1 = *(const half8*)(&Vt[kh][cur][vrow * 64 + ((kt * 4 + 2 + hi) ^ vsw) * 8]);
        o[dt] = __builtin_amdgcn_mfma_f32_32x32x16_f16(av1, f1.h, o[dt], 0, 0, 0);
      }
      __builtin_amdgcn_s_setprio(0);
    }
  }

  // finish l: add the other hi-half's partial (lanes l32 and l32+32 share q = l32)
  {
    uint32_t sx = __builtin_bit_cast(uint32_t, lsum), sy = sx;
    pl32(sx, sy);
    float oth = __builtin_bit_cast(float, (lane < 32) ? sy : sx);
    lsum += oth;
  }

  // ---- in-block kh combine through LDS scratch (reuse Kt/Vt after last tile) ----
  // scratch layout [k][wave4][lane]: conflict-free (fixed k,w -> lanes contiguous).
  uint32_t* scr = (uint32_t*)&Kt[0][0][0];   // 16 dwords/lane * 4 waves * 64 = 16 KB
  float* lscr = (float*)&Vt[0][0][0];        // 4 waves * 32 floats
  __syncthreads();                           // all LDS reads of last tile complete
  if (kh == 1) {
#pragma unroll
    for (int dt = 0; dt < 2; ++dt)
#pragma unroll
      for (int j = 0; j < 8; ++j)
        scr[(dt * 8 + j) * 256 + wq * 64 + lane] = packh2(o[dt][2 * j], o[dt][2 * j + 1]);
    if (hi == 0) lscr[wq * 32 + l32] = lsum;
  }
  __syncthreads();
  if (kh == 0) {
    const float l1 = lscr[wq * 32 + l32];
    const float inv = __builtin_amdgcn_rcpf(lsum + l1);
    const int nn = nh >> 4, h = nh & 15;
    uint16_t* xr = xg + ((size_t)(nn * 2048 + q0w + l32)) * 1024 + h * 64;
#pragma unroll
    for (int dt = 0; dt < 2; ++dt)
#pragma unroll
      for (int rg = 0; rg < 4; ++rg) {
        union { uint32_t u; _Float16 hh[2]; } u0, u1;
        u0.u = scr[(dt * 8 + rg * 2) * 256 + wq * 64 + lane];
        u1.u = scr[(dt * 8 + rg * 2 + 1) * 256 + wq * 64 + lane];
        float s0 = o[dt][rg * 4 + 0] + (float)u0.hh[0];
        float s1 = o[dt][rg * 4 + 1] + (float)u0.hh[1];
        float s2 = o[dt][rg * 4 + 2] + (float)u1.hh[0];
        float s3 = o[dt][rg * 4 + 3] + (float)u1.hh[1];
        uint2 pk;
        pk.x = pack2(s0 * inv, s1 * inv);
        pk.y = pack2(s2 * inv, s3 * inv);
        *(uint2*)(xr + dt * 32 + rg * 8 + 4 * hi) = pk;
      }
  }
}

// ---------------- out GEMM: out = X @ Wout^T + bias, 64x128 tiles -------------------
// (R9 verbatim.) Counted-vmcnt 3-buffer schedule (6 DMAs/tile/wave -> vmcnt(6)).
__global__ __launch_bounds__(256, 2) void out_gemm(const uint16_t* __restrict__ Xg,
                                                   const uint16_t* __restrict__ Wb,
                                                   const float* __restrict__ bias,
                                                   float* __restrict__ out) {
  __shared__ uint16_t Xt[3][64 * 64];
  __shared__ uint16_t Wt[3][128 * 64];
  const int t = threadIdx.x, w = t >> 6, lane = t & 63, quad = lane >> 4, l16 = lane & 15;
  const int m0 = blockIdx.x * 64, o0 = blockIdx.y * 128;
  const int srow = lane >> 3, sc8 = (lane & 7) ^ (lane >> 3);

  floatx4 acc[8];
#pragma unroll
  for (int j = 0; j < 8; ++j) acc[j] = floatx4{0.f, 0.f, 0.f, 0.f};

  auto stage = [&](int buf, int kt) {  // 6 DMA instrs/wave
#pragma unroll
    for (int i = 0; i < 2; ++i) {   // X: 16 rows/wave
      int r0 = w * 16 + i * 8;
      gl_lds16(Xg + (size_t)(m0 + r0 + srow) * 1024 + kt * 64 + sc8 * 8, &Xt[buf][r0 * 64]);
    }
#pragma unroll
    for (int i = 0; i < 4; ++i) {   // W: 32 rows/wave
      int r0 = w * 32 + i * 8;
      gl_lds16(Wb + (size_t)(o0 + r0 + srow) * 1024 + kt * 64 + sc8 * 8, &Wt[buf][r0 * 64]);
    }
  };

  stage(0, 0);
  stage(1, 1);

  int cur = 0;
  for (int kt = 0; kt < 16; ++kt) {
    if (kt + 1 < 16) asm volatile("s_waitcnt vmcnt(6)" ::: "memory");
    else             asm volatile("s_waitcnt vmcnt(0)" ::: "memory");
    __builtin_amdgcn_s_barrier();
    if (kt + 2 < 16) {
      int tgt = cur + 2; if (tgt >= 3) tgt -= 3;
      stage(tgt, kt + 2);
    }
#pragma unroll
    for (int kc = 0; kc < 2; ++kc) {
      int ra = w * 16 + l16;
      short8 a = *(const short8*)(&Xt[cur][ra * 64 + ((kc * 4 + quad) ^ (ra & 7)) * 8]);
#pragma unroll
      for (int nf = 0; nf < 8; ++nf) {
        int rb = nf * 16 + l16;
        short8 b = *(const short8*)(&Wt[cur][rb * 64 + ((kc * 4 + quad) ^ (rb & 7)) * 8]);
        acc[nf] = __builtin_amdgcn_mfma_f32_16x16x32_bf16(a, b, acc[nf], 0, 0, 0);
      }
    }
    asm volatile("s_waitcnt lgkmcnt(0)" ::: "memory");
    cur = (cur + 1 == 3) ? 0 : cur + 1;
  }

#pragma unroll
  for (int nf = 0; nf < 8; ++nf) {
    float bv = bias[o0 + nf * 16 + l16];
#pragma unroll
    for (int r = 0; r < 4; ++r)
      out[(size_t)(m0 + w * 16 + quad * 4 + r) * 1024 + o0 + nf * 16 + l16] = acc[nf][r] + bv;
  }
}

extern "C" void kernel_launch(void* const* d_in, const int* in_sizes, int n_in,
                              void* d_out, int out_size, void* d_ws, size_t ws_size,
                              hipStream_t stream) {
  const float* values = (const float*)d_in[0];
  const float* keys   = (const float*)d_in[1];
  const float* query  = (const float*)d_in[2];
  const float* Wv     = (const float*)d_in[3];
  const float* Wk     = (const float*)d_in[4];
  const float* Wq     = (const float*)d_in[5];
  const float* Wout   = (const float*)d_in[6];
  const float* bout   = (const float*)d_in[7];
  float* out = (float*)d_out;
  (void)ws_size;

  uint16_t* ws  = (uint16_t*)d_ws;
  uint16_t* qp  = ws;                                // 8 MB bf16 [nh][l][d]
  uint16_t* kp  = ws + (size_t)4194304;              // 8 MB bf16 [nh][l][d]
  uint16_t* vp  = ws + (size_t)8388608;              // 8 MB f16  [nh][d][l]
  uint16_t* wbf = ws + (size_t)12582912;             // 2 MB bf16 Wout
  uint16_t* xp  = ws + (size_t)13631488;             // 8 MB bf16 X = normalized attn out

  prep_kernel<<<dim3(1024), dim3(256), 0, stream>>>(values, keys, query, Wv, Wk, Wq, Wout,
                                                    qp, kp, vp, wbf);
  flash_kernel<<<dim3(32, 16), dim3(512), 0, stream>>>(qp, kp, vp, xp);
  out_gemm<<<dim3(64, 8), dim3(256), 0, stream>>>(xp, wbf, bout, out);
}